// Round 10
// baseline (1563.053 us; speedup 1.0000x reference)
//
#include <hip/hip_runtime.h>
#include <cmath>

#define NB 512            // 16 batch groups x 32 unit blocks
#define NT 512
#define NG 16             // groups
#define B_ 256
#define T_ 256
#define I_ 64
#define H_ 512
#define G4H 2048
#define BT 16             // batch rows per block (halved for 2 blocks/CU)
#define UT 16
#define ZP 65
#define NFC 18            // total K chunks of 32
#define NFCW 9            // K chunks per wave (K-split pair)
#define CPQ 17            // cells (16B) per q-group: 16 + 1 pad
#define CSTR 68           // cell stride per chunk (4*17)
#define NCELL 1224        // 18*68
#define HPS_STR 20
#define R_ON_F 0.05f
#define ALPHA_F 1.0e-3f
#define LN_EPS_F 1.0e-5f

typedef _Float16 h8 __attribute__((ext_vector_type(8)));
typedef _Float16 h4v __attribute__((ext_vector_type(4)));
typedef float f4 __attribute__((ext_vector_type(4)));
typedef float v4f __attribute__((ext_vector_type(4)));

// Hidden-state double buffer; all accesses bypass caches (sc0 sc1).
__device__ __align__(16) float g_h[2][B_ * H_];

struct alignas(256) PadCnt { unsigned v; unsigned pad[63]; };
__device__ PadCnt g_cnt2[NG];
__device__ PadCnt g_gen2[NG];
__device__ PadCnt g_flag[NG][32];

__device__ __forceinline__ float fast_sigmoid(float x) {
    return __builtin_amdgcn_rcpf(1.f + __expf(-x));
}
__device__ __forceinline__ float fast_tanh(float x) {
    return 1.f - 2.f * __builtin_amdgcn_rcpf(__expf(2.f * x) + 1.f);
}

struct HiLo { _Float16 hi, lo; };
__device__ __forceinline__ HiLo cvt_hilo(float v) {
    HiLo r;
    r.hi = (_Float16)v;
    r.lo = (_Float16)(v - (float)r.hi);
    return r;
}

// __launch_bounds__(512, 2): cap at 128 VGPR so 2 blocks (16 waves) co-reside per CU.
__global__ __launch_bounds__(NT, 2) void plstm_scan_kernel(
    const float* __restrict__ x, const float* __restrict__ W,
    const float* __restrict__ U, const float* __restrict__ bias,
    const float* __restrict__ tau, const float* __restrict__ sph,
    const float* __restrict__ ln_g, const float* __restrict__ ln_b,
    const float* __restrict__ W1, const float* __restrict__ b1,
    const float* __restrict__ W2, const float* __restrict__ b2,
    float* __restrict__ out)
{
    __shared__ __align__(16) _Float16 Ah[NCELL * 8];   // 19.1 KB A (fp16 hi), fragment order
    __shared__ __align__(16) float zs[2][BT][ZP];      // 8.3 KB: two K-split partials
    __shared__ __align__(16) float hps[BT * HPS_STR];  // 1.25 KB exact fp32 hprev (own 16 cols)
    __shared__ __align__(16) float bsz[64];
    __shared__ float red[16];

    const int tid = threadIdx.x;
    const int bt = blockIdx.x >> 5;    // group 0..15 (16 batch rows)
    const int ut = blockIdx.x & 31;    // unit block 0..31
    const int b0 = bt * BT;
    const int u0 = ut * UT;

    // Zero own flag FIRST (graph replay leaves stale values); step-0 atomic
    // barrier orders it group-wide.
    if (tid == 0) {
        unsigned z = 0;
        asm volatile("global_store_dword %0, %1, off sc0 sc1\n\ts_waitcnt vmcnt(0)"
                     :: "v"(&g_flag[bt][ut].v), "v"(z) : "memory");
    }

    const int wv = tid >> 6;
    const int lane = tid & 63;
    const int nt = wv >> 1;            // gate 0..3
    const int kh = wv & 1;             // K half 0..1
    const int n_ = lane & 15;
    const int q_ = lane >> 4;

    // ---- one-time: B fragments for this wave's K half, fp16 hi/lo ----
    const int jg = nt * 512 + u0 + n_;
    h8 Bh[NFCW], Bl[NFCW];
    #pragma unroll
    for (int c = 0; c < NFCW; ++c) {
        const int cg = kh * NFCW + c;
        #pragma unroll
        for (int e = 0; e < 8; ++e) {
            const int kk = cg * 32 + q_ * 8 + e;
            float v;
            if (cg < 2) v = W[(size_t)kk * G4H + jg];
            else        v = U[(size_t)(kk - I_) * G4H + jg];
            const HiLo hl = cvt_hilo(v);
            Bh[c][e] = hl.hi;
            Bl[c][e] = hl.lo;
        }
    }
    if (tid < 64) bsz[tid] = bias[((tid >> 4) << 9) + u0 + (tid & 15)];

    // gate-update layout: tid<256 -> one (row, unit)
    const int urow = tid >> 4;         // valid 0..15 for tid<256
    const int uu   = tid & 15;
    const float tau_r = tau[u0 + uu];
    const float s_r   = sph[u0 + uu];
    float c_st = 0.f;

    // staging geometry
    const int xr = (tid & 255) >> 4, xc4 = (tid & 15) << 2;       // x rows 0..15
    const int cX = (tid & 15) >> 3, qX = ((tid & 15) >> 1) & 3;
    const int e0 = (tid & 1) << 2;
    const int fX = (cX * CSTR + qX * CPQ + xr) * 8 + e0;
    const int hr0 = tid >> 7, hk4 = (tid & 127) << 2;             // h: 4 rows x 1 float4
    const int cS = 2 + ((tid & 127) >> 3), qS = ((tid & 127) >> 1) & 3;
    const int mloc = (tid & 127) - (u0 >> 2);
    const bool own = (mloc >= 0) && (mloc < 4);
    const int dof = mloc << 2;

    float4 xv = *(const float4*)(x + ((size_t)(b0 + xr) * T_ + 0) * I_ + xc4);

    // MFMA A-frag read base for this wave (fragment-order)
    const int fb = (kh * NFCW * CSTR + q_ * CPQ + n_) * 8;

    int cur = 0;
    for (int t = 0; t < T_; ++t) {
        // ---- A) stage operands ----
        if (t == 0) {
            const h8 z8 = {};
            for (int idx = tid; idx < NCELL; idx += NT)
                *(h8*)&Ah[idx * 8] = z8;
            if (tid < (BT * HPS_STR) / 4) {
                const v4f zf = {0.f, 0.f, 0.f, 0.f};
                *(v4f*)&hps[tid * 4] = zf;
            }
            __syncthreads();
            if (tid < 256) {
                h4v xh;
                xh[0] = (_Float16)xv.x; xh[1] = (_Float16)xv.y;
                xh[2] = (_Float16)xv.z; xh[3] = (_Float16)xv.w;
                *(h4v*)&Ah[fX] = xh;
            }
        } else {
            const float* hb = g_h[cur] + (size_t)(b0 + hr0) * H_ + hk4;
            v4f a0, a1, a2, a3;
            asm volatile(
                "global_load_dwordx4 %0, %4, off sc0 sc1\n\t"
                "global_load_dwordx4 %1, %5, off sc0 sc1\n\t"
                "global_load_dwordx4 %2, %6, off sc0 sc1\n\t"
                "global_load_dwordx4 %3, %7, off sc0 sc1"
                : "=&v"(a0), "=&v"(a1), "=&v"(a2), "=&v"(a3)
                : "v"(hb), "v"(hb + 4 * H_), "v"(hb + 8 * H_), "v"(hb + 12 * H_)
                : "memory");
            asm volatile("s_waitcnt vmcnt(0)"
                : "+v"(a0), "+v"(a1), "+v"(a2), "+v"(a3) :: "memory");
            const v4f av[4] = {a0, a1, a2, a3};
            #pragma unroll
            for (int it = 0; it < 4; ++it) {
                const int row = hr0 + 4 * it;
                const int fidx = (cS * CSTR + qS * CPQ + row) * 8 + e0;
                h4v hh;
                hh[0] = (_Float16)av[it][0]; hh[1] = (_Float16)av[it][1];
                hh[2] = (_Float16)av[it][2]; hh[3] = (_Float16)av[it][3];
                *(h4v*)&Ah[fidx] = hh;
                if (own) *(v4f*)&hps[row * HPS_STR + dof] = av[it];
            }
        }
        __syncthreads();                                   // S1

        // prefetch next x
        if (tid < 256) {
            const int tn = (t < T_ - 1) ? t + 1 : t;
            xv = *(const float4*)(x + ((size_t)(b0 + xr) * T_ + tn) * I_ + xc4);
        }

        // ---- B) MFMA: A-hi x (B-hi + B-lo), K-split halves ----
        f4 ac0 = {0.f, 0.f, 0.f, 0.f};
        f4 ac1 = {0.f, 0.f, 0.f, 0.f};
        #pragma unroll
        for (int c = 0; c < NFCW; ++c) {
            const h8 ah = *(const h8*)&Ah[fb + c * (CSTR * 8)];
            ac0 = __builtin_amdgcn_mfma_f32_16x16x32_f16(ah, Bh[c], ac0, 0, 0, 0);
            ac1 = __builtin_amdgcn_mfma_f32_16x16x32_f16(ah, Bl[c], ac1, 0, 0, 0);
        }
        const f4 zt = ac0 + ac1;
        {
            const int colz = nt * 16 + n_;
            const int rz = q_ * 4;     // C-layout: row=(lane>>4)*4+reg (M=16)
            zs[kh][rz + 0][colz] = zt[0];
            zs[kh][rz + 1][colz] = zt[1];
            zs[kh][rz + 2][colz] = zt[2];
            zs[kh][rz + 3][colz] = zt[3];
        }
        __syncthreads();                                   // S2

        // ---- C) gates + phased time-gate; store h (tid<256) ----
        if (tid < 256) {
            const float zi = zs[0][urow][uu]      + zs[1][urow][uu]      + bsz[uu];
            const float zf = zs[0][urow][16 + uu] + zs[1][urow][16 + uu] + bsz[16 + uu];
            const float zg = zs[0][urow][32 + uu] + zs[1][urow][32 + uu] + bsz[32 + uu];
            const float zo = zs[0][urow][48 + uu] + zs[1][urow][48 + uu] + bsz[48 + uu];
            const float si = fast_sigmoid(zi);
            const float sf = fast_sigmoid(zf);
            const float so = fast_sigmoid(zo);
            const float ct = sf * c_st + si * fast_tanh(zg);
            const float ht = so * fast_tanh(ct);
            float aa = (float)t - s_r;
            float rr = fmodf(aa, tau_r);
            if (rr < 0.f) rr += tau_r;
            const float phi = rr / tau_r;
            float kk;
            if (phi < 0.5f * R_ON_F)      kk = phi * (2.f / R_ON_F);
            else if (phi < R_ON_F)        kk = 2.f - phi * (2.f / R_ON_F);
            else                          kk = ALPHA_F * phi;
            const float hprev = hps[urow * HPS_STR + uu];  // exact fp32
            const float hn = kk * ht + (1.f - kk) * hprev;
            c_st = kk * ct + (1.f - kk) * c_st;
            float* gp = g_h[cur ^ 1] + (size_t)(b0 + urow) * H_ + (u0 + uu);
            asm volatile("global_store_dword %0, %1, off sc0 sc1\n\ts_waitcnt vmcnt(0)"
                         :: "v"(gp), "v"(hn) : "memory");
        }
        __syncthreads();                                   // S3: all h stores drained

        // ---- D) publish flag + overlap x staging + single-hop wait ----
        if (t > 0 && tid == 0) {
            unsigned fv = (unsigned)(t + 1);
            asm volatile("global_store_dword %0, %1, off sc0 sc1"
                         :: "v"(&g_flag[bt][ut].v), "v"(fv) : "memory");
        }
        if (t < T_ - 1 && tid < 256) {
            h4v xh;
            xh[0] = (_Float16)xv.x; xh[1] = (_Float16)xv.y;
            xh[2] = (_Float16)xv.z; xh[3] = (_Float16)xv.w;
            *(h4v*)&Ah[fX] = xh;
        }
        if (t == 0) {
            if (tid == 0) {
                unsigned gen = __hip_atomic_load(&g_gen2[bt].v, __ATOMIC_RELAXED, __HIP_MEMORY_SCOPE_SYSTEM);
                unsigned a = __hip_atomic_fetch_add(&g_cnt2[bt].v, 1u, __ATOMIC_RELAXED, __HIP_MEMORY_SCOPE_SYSTEM);
                if (a == 31u) {
                    __hip_atomic_store(&g_cnt2[bt].v, 0u, __ATOMIC_RELAXED, __HIP_MEMORY_SCOPE_SYSTEM);
                    asm volatile("s_waitcnt vmcnt(0)" ::: "memory");
                    __hip_atomic_store(&g_gen2[bt].v, gen + 1u, __ATOMIC_RELAXED, __HIP_MEMORY_SCOPE_SYSTEM);
                } else {
                    while (__hip_atomic_load(&g_gen2[bt].v, __ATOMIC_RELAXED, __HIP_MEMORY_SCOPE_SYSTEM) == gen)
                        __builtin_amdgcn_s_sleep(1);
                }
            }
        } else if (tid < 64) {
            const unsigned want = (unsigned)(t + 1);
            const unsigned* fp = &g_flag[bt][tid & 31].v;
            unsigned v;
            do {
                asm volatile("global_load_dword %0, %1, off sc0 sc1\n\ts_waitcnt vmcnt(0)"
                             : "=v"(v) : "v"(fp) : "memory");
            } while (__ballot(v < want));
        }
        __syncthreads();                                   // S4
        cur ^= 1;
    }

    // ---- epilogue: blocks with ut<16 handle batch row bt*16+ut ----
    if (ut < BT) {
        const int b = bt * BT + ut;
        float hv;
        const float* hp = g_h[cur] + (size_t)b * H_ + tid;
        asm volatile("global_load_dword %0, %1, off sc0 sc1\n\ts_waitcnt vmcnt(0)"
                     : "=v"(hv) : "v"(hp) : "memory");
        float s1 = hv, s2 = hv * hv;
        #pragma unroll
        for (int off = 32; off > 0; off >>= 1) {
            s1 += __shfl_down(s1, off, 64);
            s2 += __shfl_down(s2, off, 64);
        }
        const int ln = tid & 63;
        if (ln == 0) { red[wv] = s1; red[8 + wv] = s2; }
        __syncthreads();
        float S1 = 0.f, S2 = 0.f;
        #pragma unroll
        for (int w = 0; w < 8; ++w) { S1 += red[w]; S2 += red[8 + w]; }
        const float mu = S1 * (1.f / 512.f);
        const float var = S2 * (1.f / 512.f) - mu * mu;
        const float rstd = rsqrtf(var + LN_EPS_F);
        const float hn = (hv - mu) * rstd * ln_g[tid] + ln_b[tid];
        float w12 = 0.f;
        const float* w1p = W1 + (size_t)tid * 256;
        #pragma unroll 4
        for (int d = 0; d < 256; ++d) w12 = fmaf(w1p[d], W2[d], w12);
        float contrib = hn * w12;
        if (tid < 256) contrib = fmaf(b1[tid], W2[tid], contrib);
        #pragma unroll
        for (int off = 32; off > 0; off >>= 1) contrib += __shfl_down(contrib, off, 64);
        __syncthreads();
        if (ln == 0) red[wv] = contrib;
        __syncthreads();
        if (tid == 0) {
            float tot = b2[0];
            #pragma unroll
            for (int w = 0; w < 8; ++w) tot += red[w];
            out[b] = tot;
        }
    }
}

extern "C" void kernel_launch(void* const* d_in, const int* in_sizes, int n_in,
                              void* d_out, int out_size, void* d_ws, size_t ws_size,
                              hipStream_t stream) {
    const float* x   = (const float*)d_in[0];
    const float* W   = (const float*)d_in[1];
    const float* U   = (const float*)d_in[2];
    const float* b   = (const float*)d_in[3];
    const float* tau = (const float*)d_in[4];
    const float* s   = (const float*)d_in[5];
    const float* lng = (const float*)d_in[6];
    const float* lnb = (const float*)d_in[7];
    const float* W1  = (const float*)d_in[8];
    const float* b1  = (const float*)d_in[9];
    const float* W2  = (const float*)d_in[10];
    const float* b2  = (const float*)d_in[11];
    float* out = (float*)d_out;
    plstm_scan_kernel<<<dim3(NB), dim3(NT), 0, stream>>>(
        x, W, U, b, tau, s, lng, lnb, W1, b1, W2, b2, out);
}

// Round 11
// 893.530 us; speedup vs baseline: 1.7493x; 1.7493x over previous
//
#include <hip/hip_runtime.h>
#include <cmath>

#define NB 256            // 16 batch groups x 16 unit blocks -> 1 block/CU (known-good regime)
#define NT 512
#define NG 16             // batch groups
#define GB 16             // blocks per group
#define B_ 256
#define T_ 256
#define I_ 64
#define H_ 512
#define G4H 2048
#define BT 16             // batch rows per block (light h-exchange: 4 loads/thread)
#define UT 32             // hidden units per block -> 128 z cols, 8 waves = 8 N-tiles
#define ZP 132            // zs row stride (128 + 4)
#define NFC 18            // K chunks of 32
#define CPQ 17            // cells (16B) per q-group: 16 rows + 1 pad
#define CSTR 68           // cell stride per chunk (4*17)
#define NCELL 1224        // 18*68
#define HPS_STR 36        // fp32 hprev sidecar row stride (32 + 4)
#define R_ON_F 0.05f
#define ALPHA_F 1.0e-3f
#define LN_EPS_F 1.0e-5f

typedef _Float16 h8 __attribute__((ext_vector_type(8)));
typedef _Float16 h4v __attribute__((ext_vector_type(4)));
typedef float f4 __attribute__((ext_vector_type(4)));
typedef float v4f __attribute__((ext_vector_type(4)));

// Hidden-state double buffer; all accesses bypass caches (sc0 sc1).
__device__ __align__(16) float g_h[2][B_ * H_];

struct alignas(256) PadCnt { unsigned v; unsigned pad[63]; };
__device__ PadCnt g_cnt2[NG];
__device__ PadCnt g_gen2[NG];
__device__ PadCnt g_flag[NG][GB];  // flag[g][ut] = t+1 when block's h(t+1) stores drained

__device__ __forceinline__ float fast_sigmoid(float x) {
    return __builtin_amdgcn_rcpf(1.f + __expf(-x));
}
__device__ __forceinline__ float fast_tanh(float x) {
    return 1.f - 2.f * __builtin_amdgcn_rcpf(__expf(2.f * x) + 1.f);
}

struct HiLo { _Float16 hi, lo; };
__device__ __forceinline__ HiLo cvt_hilo(float v) {
    HiLo r;
    r.hi = (_Float16)v;
    r.lo = (_Float16)(v - (float)r.hi);
    return r;
}

__global__ __launch_bounds__(NT, 1) void plstm_scan_kernel(
    const float* __restrict__ x, const float* __restrict__ W,
    const float* __restrict__ U, const float* __restrict__ bias,
    const float* __restrict__ tau, const float* __restrict__ sph,
    const float* __restrict__ ln_g, const float* __restrict__ ln_b,
    const float* __restrict__ W1, const float* __restrict__ b1,
    const float* __restrict__ W2, const float* __restrict__ b2,
    float* __restrict__ out)
{
    __shared__ __align__(16) _Float16 Ah[NCELL * 8];   // 19.1 KB A (fp16 hi), fragment order
    __shared__ __align__(16) float zs[BT][ZP];         // 8.25 KB z tile (no K-split)
    __shared__ __align__(16) float hps[BT * HPS_STR];  // 2.25 KB exact fp32 hprev (own 32 cols)
    __shared__ __align__(16) float bsz[128];
    __shared__ float red[16];

    const int tid = threadIdx.x;
    const int bt = blockIdx.x >> 4;    // batch group 0..15
    const int ut = blockIdx.x & 15;    // unit block 0..15
    const int b0 = bt * BT;
    const int u0 = ut * UT;

    // Zero own flag FIRST (graph replay leaves stale values); the step-0
    // atomic barrier orders it group-wide before any t>=2 poll can observe.
    if (tid == 0) {
        unsigned z = 0;
        asm volatile("global_store_dword %0, %1, off sc0 sc1\n\ts_waitcnt vmcnt(0)"
                     :: "v"(&g_flag[bt][ut].v), "v"(z) : "memory");
    }

    const int wv = tid >> 6;           // wave = N-tile 0..7
    const int lane = tid & 63;
    const int n_ = lane & 15;
    const int q_ = lane >> 4;

    // ---- one-time: B fragments (this wave's 16 cols), fp16 hi/lo ----
    const int jg = (wv >> 1) * 512 + u0 + (wv & 1) * 16 + n_;
    h8 Bh[NFC], Bl[NFC];
    #pragma unroll
    for (int c = 0; c < NFC; ++c) {
        #pragma unroll
        for (int e = 0; e < 8; ++e) {
            const int kk = c * 32 + q_ * 8 + e;
            float v;
            if (c < 2) v = W[(size_t)kk * G4H + jg];
            else       v = U[(size_t)(kk - I_) * G4H + jg];
            const HiLo hl = cvt_hilo(v);
            Bh[c][e] = hl.hi;
            Bl[c][e] = hl.lo;
        }
    }
    if (tid < 128) bsz[tid] = bias[((tid >> 5) << 9) + u0 + (tid & 31)];

    // gate-update layout: all 512 threads -> (row 0..15, unit 0..31)
    const int urow = tid >> 5;
    const int uu   = tid & 31;
    const float tau_r = tau[u0 + uu];
    const float s_r   = sph[u0 + uu];
    float c_st = 0.f;

    // staging geometry
    const int xr = (tid >> 4) & 15, xc4 = (tid & 15) << 2;  // x: tid<256, 1 float4
    const int cX = (tid & 15) >> 3, qX = ((tid & 15) >> 1) & 3;
    const int e0 = (tid & 1) << 2;
    const int fX = (cX * CSTR + qX * CPQ + xr) * 8 + e0;
    const int hr0 = tid >> 7, hk4 = (tid & 127) << 2;       // h: 4 rows x 1 float4
    const int cS = 2 + ((tid & 127) >> 3), qS = ((tid & 127) >> 1) & 3;
    const int srcblk = (tid & 127) >> 3;                    // writer block of my 4 cols
    const int mloc = (tid & 127) - (u0 >> 2);
    const bool own = (mloc >= 0) && (mloc < 8);
    const int dof = mloc << 2;

    float4 xv = *(const float4*)(x + ((size_t)(b0 + xr) * T_ + 0) * I_ + xc4);

    // MFMA A-frag read base (fragment order; same A broadcast to all 8 waves)
    const int fb = (q_ * CPQ + n_) * 8;

    int cur = 0;
    for (int t = 0; t < T_; ++t) {
        // ---- A) stage operands (per-thread dataflow poll, no extra barrier) ----
        if (t == 0) {
            const h8 z8 = {};
            for (int idx = tid; idx < NCELL; idx += NT)
                *(h8*)&Ah[idx * 8] = z8;
            if (tid < (BT * HPS_STR) / 4) {
                const v4f zf = {0.f, 0.f, 0.f, 0.f};
                *(v4f*)&hps[tid * 4] = zf;
            }
            __syncthreads();
            if (tid < 256) {
                h4v xh;
                xh[0] = (_Float16)xv.x; xh[1] = (_Float16)xv.y;
                xh[2] = (_Float16)xv.z; xh[3] = (_Float16)xv.w;
                *(h4v*)&Ah[fX] = xh;
            }
        } else {
            if (t >= 2) {
                // wait only for MY source block's flag (t==1 covered by barrier)
                const unsigned want = (unsigned)t;
                const unsigned* fp = &g_flag[bt][srcblk].v;
                unsigned v;
                do {
                    asm volatile("global_load_dword %0, %1, off sc0 sc1\n\ts_waitcnt vmcnt(0)"
                                 : "=v"(v) : "v"(fp) : "memory");
                } while (__ballot(v < want));
            }
            const float* hb = g_h[cur] + (size_t)(b0 + hr0) * H_ + hk4;
            v4f a0, a1, a2, a3;
            asm volatile(
                "global_load_dwordx4 %0, %4, off sc0 sc1\n\t"
                "global_load_dwordx4 %1, %5, off sc0 sc1\n\t"
                "global_load_dwordx4 %2, %6, off sc0 sc1\n\t"
                "global_load_dwordx4 %3, %7, off sc0 sc1"
                : "=&v"(a0), "=&v"(a1), "=&v"(a2), "=&v"(a3)
                : "v"(hb), "v"(hb + 4 * H_), "v"(hb + 8 * H_), "v"(hb + 12 * H_)
                : "memory");
            asm volatile("s_waitcnt vmcnt(0)"
                : "+v"(a0), "+v"(a1), "+v"(a2), "+v"(a3) :: "memory");
            const v4f av[4] = {a0, a1, a2, a3};
            #pragma unroll
            for (int it = 0; it < 4; ++it) {
                const int row = hr0 + 4 * it;
                const int fidx = (cS * CSTR + qS * CPQ + row) * 8 + e0;
                h4v hh;
                hh[0] = (_Float16)av[it][0]; hh[1] = (_Float16)av[it][1];
                hh[2] = (_Float16)av[it][2]; hh[3] = (_Float16)av[it][3];
                *(h4v*)&Ah[fidx] = hh;
                if (own) *(v4f*)&hps[row * HPS_STR + dof] = av[it];
            }
        }
        __syncthreads();                                   // S1

        // prefetch next x
        if (tid < 256) {
            const int tn = (t < T_ - 1) ? t + 1 : t;
            xv = *(const float4*)(x + ((size_t)(b0 + xr) * T_ + tn) * I_ + xc4);
        }

        // ---- B) MFMA: A-hi x (B-hi + B-lo) ----
        f4 ac0 = {0.f, 0.f, 0.f, 0.f};
        f4 ac1 = {0.f, 0.f, 0.f, 0.f};
        #pragma unroll
        for (int c = 0; c < NFC; ++c) {
            const h8 ah = *(const h8*)&Ah[fb + c * (CSTR * 8)];
            ac0 = __builtin_amdgcn_mfma_f32_16x16x32_f16(ah, Bh[c], ac0, 0, 0, 0);
            ac1 = __builtin_amdgcn_mfma_f32_16x16x32_f16(ah, Bl[c], ac1, 0, 0, 0);
        }
        const f4 zt = ac0 + ac1;
        {
            const int colz = wv * 16 + n_;
            const int rz = q_ * 4;     // C-layout: row=(lane>>4)*4+reg (M=16)
            zs[rz + 0][colz] = zt[0];
            zs[rz + 1][colz] = zt[1];
            zs[rz + 2][colz] = zt[2];
            zs[rz + 3][colz] = zt[3];
        }
        __syncthreads();                                   // S2

        // ---- C) gates + phased time-gate; store h (all 512 threads) ----
        {
            const float zi = zs[urow][uu]       + bsz[uu];
            const float zf = zs[urow][32 + uu]  + bsz[32 + uu];
            const float zg = zs[urow][64 + uu]  + bsz[64 + uu];
            const float zo = zs[urow][96 + uu]  + bsz[96 + uu];
            const float si = fast_sigmoid(zi);
            const float sf = fast_sigmoid(zf);
            const float so = fast_sigmoid(zo);
            const float ct = sf * c_st + si * fast_tanh(zg);
            const float ht = so * fast_tanh(ct);
            float aa = (float)t - s_r;
            float rr = fmodf(aa, tau_r);
            if (rr < 0.f) rr += tau_r;
            const float phi = rr / tau_r;
            float kk;
            if (phi < 0.5f * R_ON_F)      kk = phi * (2.f / R_ON_F);
            else if (phi < R_ON_F)        kk = 2.f - phi * (2.f / R_ON_F);
            else                          kk = ALPHA_F * phi;
            const float hprev = hps[urow * HPS_STR + uu];  // exact fp32
            const float hn = kk * ht + (1.f - kk) * hprev;
            c_st = kk * ct + (1.f - kk) * c_st;
            float* gp = g_h[cur ^ 1] + (size_t)(b0 + urow) * H_ + (u0 + uu);
            asm volatile("global_store_dword %0, %1, off sc0 sc1\n\ts_waitcnt vmcnt(0)"
                         :: "v"(gp), "v"(hn) : "memory");
        }
        __syncthreads();                                   // S3: all h stores drained

        // ---- D) publish + overlapped x staging + (t==0) launch-safe barrier ----
        if (tid == 0) {
            unsigned fv = (unsigned)(t + 1);
            asm volatile("global_store_dword %0, %1, off sc0 sc1"
                         :: "v"(&g_flag[bt][ut].v), "v"(fv) : "memory");
        }
        if (t < T_ - 1 && tid < 256) {
            h4v xh;
            xh[0] = (_Float16)xv.x; xh[1] = (_Float16)xv.y;
            xh[2] = (_Float16)xv.z; xh[3] = (_Float16)xv.w;
            *(h4v*)&Ah[fX] = xh;
        }
        if (t == 0) {
            // once-only atomic barrier: orders flag zeroing + h(1) group-wide
            if (tid == 0) {
                unsigned gen = __hip_atomic_load(&g_gen2[bt].v, __ATOMIC_RELAXED, __HIP_MEMORY_SCOPE_SYSTEM);
                unsigned a = __hip_atomic_fetch_add(&g_cnt2[bt].v, 1u, __ATOMIC_RELAXED, __HIP_MEMORY_SCOPE_SYSTEM);
                if (a == GB - 1u) {
                    __hip_atomic_store(&g_cnt2[bt].v, 0u, __ATOMIC_RELAXED, __HIP_MEMORY_SCOPE_SYSTEM);
                    asm volatile("s_waitcnt vmcnt(0)" ::: "memory");
                    __hip_atomic_store(&g_gen2[bt].v, gen + 1u, __ATOMIC_RELAXED, __HIP_MEMORY_SCOPE_SYSTEM);
                } else {
                    while (__hip_atomic_load(&g_gen2[bt].v, __ATOMIC_RELAXED, __HIP_MEMORY_SCOPE_SYSTEM) == gen)
                        __builtin_amdgcn_s_sleep(1);
                }
            }
            __syncthreads();
        }
        cur ^= 1;
    }

    // ---- epilogue: block b handles batch row b: LN + collapsed dense head ----
    {
        // wait for the whole group's final h stores (flags reach T_)
        if (tid < 64) {
            const unsigned want = (unsigned)T_;
            const unsigned* fp = &g_flag[bt][tid & 15].v;
            unsigned v;
            do {
                asm volatile("global_load_dword %0, %1, off sc0 sc1\n\ts_waitcnt vmcnt(0)"
                             : "=v"(v) : "v"(fp) : "memory");
            } while (__ballot(v < want));
        }
        __syncthreads();

        const int b = blockIdx.x;
        float hv;
        const float* hp = g_h[cur] + (size_t)b * H_ + tid;
        asm volatile("global_load_dword %0, %1, off sc0 sc1\n\ts_waitcnt vmcnt(0)"
                     : "=v"(hv) : "v"(hp) : "memory");
        float s1 = hv, s2 = hv * hv;
        #pragma unroll
        for (int off = 32; off > 0; off >>= 1) {
            s1 += __shfl_down(s1, off, 64);
            s2 += __shfl_down(s2, off, 64);
        }
        const int ln = tid & 63;
        if (ln == 0) { red[wv] = s1; red[8 + wv] = s2; }
        __syncthreads();
        float S1 = 0.f, S2 = 0.f;
        #pragma unroll
        for (int w = 0; w < 8; ++w) { S1 += red[w]; S2 += red[8 + w]; }
        const float mu = S1 * (1.f / 512.f);
        const float var = S2 * (1.f / 512.f) - mu * mu;
        const float rstd = rsqrtf(var + LN_EPS_F);
        const float hn = (hv - mu) * rstd * ln_g[tid] + ln_b[tid];
        float w12 = 0.f;
        const float* w1p = W1 + (size_t)tid * 256;
        #pragma unroll 4
        for (int d = 0; d < 256; ++d) w12 = fmaf(w1p[d], W2[d], w12);
        float contrib = hn * w12;
        if (tid < 256) contrib = fmaf(b1[tid], W2[tid], contrib);
        #pragma unroll
        for (int off = 32; off > 0; off >>= 1) contrib += __shfl_down(contrib, off, 64);
        __syncthreads();
        if (ln == 0) red[wv] = contrib;
        __syncthreads();
        if (tid == 0) {
            float tot = b2[0];
            #pragma unroll
            for (int w = 0; w < 8; ++w) tot += red[w];
            out[b] = tot;
        }
    }
}

extern "C" void kernel_launch(void* const* d_in, const int* in_sizes, int n_in,
                              void* d_out, int out_size, void* d_ws, size_t ws_size,
                              hipStream_t stream) {
    const float* x   = (const float*)d_in[0];
    const float* W   = (const float*)d_in[1];
    const float* U   = (const float*)d_in[2];
    const float* b   = (const float*)d_in[3];
    const float* tau = (const float*)d_in[4];
    const float* s   = (const float*)d_in[5];
    const float* lng = (const float*)d_in[6];
    const float* lnb = (const float*)d_in[7];
    const float* W1  = (const float*)d_in[8];
    const float* b1  = (const float*)d_in[9];
    const float* W2  = (const float*)d_in[10];
    const float* b2  = (const float*)d_in[11];
    float* out = (float*)d_out;
    plstm_scan_kernel<<<dim3(NB), dim3(NT), 0, stream>>>(
        x, W, U, b, tau, s, lng, lnb, W1, b1, W2, b2, out);
}